// Round 13
// baseline (199.591 us; speedup 1.0000x reference)
//
#include <hip/hip_runtime.h>
#include <hip/hip_bf16.h>
#include <stdint.h>

#define M_DIM 8192
#define N_DIM 4096
#define K_DIM 4096

#define NT 64              // K-tiles of BK=64

using i32x4 = __attribute__((ext_vector_type(4))) int;

typedef const __attribute__((address_space(1))) void glb_void_t;
typedef __attribute__((address_space(3))) void lds_void_t;

__device__ __forceinline__ void async16(const void* g, void* l) {
    // direct global->LDS, 16B per lane (dest = wave-uniform base + lane*16)
    __builtin_amdgcn_global_load_lds((glb_void_t*)(uintptr_t)g,
                                     (lds_void_t*)(uint32_t)(uintptr_t)l,
                                     16, 0, 0);
}

__device__ __forceinline__ int sgn_i8(float f) {
    union { float f; uint32_t u; } v; v.f = f;
    if ((v.u & 0x7FFFFFFFu) == 0u) return 0;          // sign(0) = 0
    return (v.u >> 31) ? -1 : 1;
}

// ---- Phase 1a: W sign -> i8 {-1,0,+1}, RETILED [nb][kt][64 rows][64 k] ----
// GEMM reads B fragments directly from global: a wave's frag is a contiguous
// 1KB within one [64][64] tile -> dense coalescing without LDS.

__global__ void convert_w_kernel(const float* __restrict__ w,
                                 unsigned char* __restrict__ wq, int n4) {
    int stride = gridDim.x * blockDim.x;
    for (int i = blockIdx.x * blockDim.x + threadIdx.x; i < n4; i += stride) {
        float4 v = ((const float4*)w)[i];
        uint32_t o = ((uint32_t)(uint8_t)sgn_i8(v.x)) |
                     ((uint32_t)(uint8_t)sgn_i8(v.y) << 8) |
                     ((uint32_t)(uint8_t)sgn_i8(v.z) << 16) |
                     ((uint32_t)(uint8_t)sgn_i8(v.w) << 24);
        const int flat = i * 4;
        const int row  = flat >> 12;          // output feature
        const int k    = flat & 4095;
        const size_t dst = ((size_t)(row >> 6) << 18) + ((k >> 6) << 12) +
                           ((row & 63) << 6) + (k & 63);
        *(uint32_t*)(wq + dst) = o;
    }
}

// ---- Phase 1b: X per-row i8 quant (fused max + quantize, single pass) ----

__global__ __launch_bounds__(256)
void convert_x_kernel(const float* __restrict__ x,
                      unsigned char* __restrict__ xq,
                      float* __restrict__ scales) {
    const int row = blockIdx.x;
    const int tid = threadIdx.x;
    const float4* xr = (const float4*)(x + (size_t)row * K_DIM);
    float4 v[4];
    float m = 0.f;
    #pragma unroll
    for (int j = 0; j < 4; ++j) {
        v[j] = xr[j * 256 + tid];
        m = fmaxf(m, fmaxf(fmaxf(fabsf(v[j].x), fabsf(v[j].y)),
                           fmaxf(fabsf(v[j].z), fabsf(v[j].w))));
    }
    #pragma unroll
    for (int off = 32; off >= 1; off >>= 1)
        m = fmaxf(m, __shfl_xor(m, off));
    __shared__ float wmax[4];
    if ((tid & 63) == 0) wmax[tid >> 6] = m;
    __syncthreads();
    m = fmaxf(fmaxf(wmax[0], wmax[1]), fmaxf(wmax[2], wmax[3]));
    const float inv = (m > 0.f) ? 127.0f / m : 0.f;
    if (tid == 0) scales[row] = (m > 0.f) ? m / 127.0f : 0.f;
    uint32_t* oq = (uint32_t*)(xq + (size_t)row * K_DIM);
    #pragma unroll
    for (int j = 0; j < 4; ++j) {
        float q0 = fminf(fmaxf(rintf(v[j].x * inv), -127.f), 127.f);
        float q1 = fminf(fmaxf(rintf(v[j].y * inv), -127.f), 127.f);
        float q2 = fminf(fmaxf(rintf(v[j].z * inv), -127.f), 127.f);
        float q3 = fminf(fmaxf(rintf(v[j].w * inv), -127.f), 127.f);
        uint32_t o = ((uint32_t)(uint8_t)(int)q0) |
                     ((uint32_t)(uint8_t)(int)q1 << 8) |
                     ((uint32_t)(uint8_t)(int)q2 << 16) |
                     ((uint32_t)(uint8_t)(int)q3 << 24);
        oq[j * 256 + tid] = o;
    }
}

// ---- Phase 2: 256x256-tile i8 GEMM, A via LDS, B via global->register ----
// Round 13: LDS-pipe was the wall (128KB/tile traffic ~1540cyc > MFMA 1306).
// B fragments now load straight from retiled wq (L2/L3-resident) into regs:
// LDS traffic drops to A only (64KB reads + 16KB writes ~ 960 cyc < MFMA).
// LDS: [4 buf][2 sect: A0,A1][128 x 64 i8] = 64 KiB; buf = T&3; tile T stages
// A of T+3. T2 chunk-XOR swizzle on A (round-8-proven, 0 conflicts).
// Sync (1 raw barrier/tile; compiler auto-waits do the ledger):
//   B(T) regs (typed loads, issued T-1) force a compiler vmcnt before tile
//   T's first MFMA; in-order vmcnt drain => everything older - including
//   A(T+1)'s stages from T-2 - is complete before BAR(T-1)/BAR(T) publish.
//   A-buf WAR: buf (T+3)&3's readers (tile T-2 ds_reads) are consumed by
//   T-1's MFMAs (lgkm auto-wait) before BAR(T-1) < tile-T stages.

#define BAR   __builtin_amdgcn_s_barrier()
#define VM8   asm volatile("s_waitcnt vmcnt(8)" ::: "memory")

// stage A half-tiles of tile T into buf T&3
#define STGA(T) do { \
    const int pb_ = (T) & 3; \
    stage(pb_, 0, xq, brow,       (T) * 64); \
    stage(pb_, 1, xq, brow + 128, (T) * 64); \
} while (0)

// load B fragments of tile T straight into register set BV
#define BLOAD(BV, T) do { \
    _Pragma("unroll") for (int nn = 0; nn < 4; ++nn) \
        BV[nn] = *(const i32x4*)(bptr + (size_t)(T) * 4096 + nn * 1024); \
} while (0)

// read all 8 A fragments of tile T into register set AV  [tail use]
#define RDSETA(AV, T) do { \
    const int rb_ = (T) & 3; \
    _Pragma("unroll") for (int mm = 0; mm < 8; ++mm) \
        AV[mm] = rdA(rb_, mm * 16); \
} while (0)

// all 32 MFMAs of one tile  [tail use]
#define MMA(AV, BV) do { \
    __builtin_amdgcn_s_setprio(1); \
    _Pragma("unroll") for (int mm = 0; mm < 8; ++mm) \
    _Pragma("unroll") for (int nn = 0; nn < 4; ++nn) \
        acc[mm][nn] = __builtin_amdgcn_mfma_i32_16x16x64_i8( \
            AV[mm], BV[nn], acc[mm][nn], 0, 0, 0); \
    __builtin_amdgcn_s_setprio(0); \
} while (0)

// 8 MFMAs (2 m-rows)
#define MM2(AV, BV, M0) \
    _Pragma("unroll") for (int mm = (M0); mm < (M0) + 2; ++mm) \
    _Pragma("unroll") for (int nn = 0; nn < 4; ++nn) \
        acc[mm][nn] = __builtin_amdgcn_mfma_i32_16x16x64_i8( \
            AV[mm], BV[nn], acc[mm][nn], 0, 0, 0);

// steady-state tile T: MFMA tile T from (CA,CB); A-reads of T+1 into NA;
// B-loads of T+1 into NB; stage A(T+3).
#define ITILE(CA, CB, NA, NB, T) do { \
    const int rb_ = ((T) + 1) & 3; \
    STGA((T) + 3); \
    BLOAD(NB, (T) + 1); \
    __builtin_amdgcn_s_setprio(1); \
    NA[0] = rdA(rb_,  0); NA[1] = rdA(rb_, 16); \
    MM2(CA, CB, 0) \
    NA[2] = rdA(rb_, 32); NA[3] = rdA(rb_, 48); \
    MM2(CA, CB, 2) \
    NA[4] = rdA(rb_, 64); NA[5] = rdA(rb_, 80); \
    MM2(CA, CB, 4) \
    NA[6] = rdA(rb_, 96); NA[7] = rdA(rb_, 112); \
    MM2(CA, CB, 6) \
    __builtin_amdgcn_s_setprio(0); \
    BAR; \
} while (0)

__global__ __launch_bounds__(512, 2)
void gemm_bin_kernel(const unsigned char* __restrict__ xq,
                     const unsigned char* __restrict__ wq,
                     const float* __restrict__ scales,
                     const float* __restrict__ bias,
                     float* __restrict__ out) {
    __shared__ __align__(16) unsigned char lds[4][2][8192];

    const int tid  = threadIdx.x;
    const int wid  = tid >> 6;
    const int lane = tid & 63;

    // XCD-aware swizzle: 512 blocks, 8 XCDs, 64 contiguous tiles per XCD
    const int bid  = blockIdx.x;
    const int swzb = (bid & 7) * 64 + (bid >> 3);
    const int brow = (swzb >> 4) * 256;      // 32 M-tiles
    const int bcol = (swzb & 15) * 256;      // 16 N-tiles

    const int wm = wid >> 2;                 // 0..1: A half (row block of 128)
    const int wn = wid & 3;                  // 0..3: 64-col block
    const int fr  = lane & 15;
    const int g16 = (lane >> 4) << 4;        // logical k-chunk byte offset
    const int sw  = ((lane >> 1) & 3) << 4;  // T2: ((row>>1)&3)<<4, row=fr+16m

    // B pointer: retiled wq, this wave's 64-col block, per-lane frag offset
    const int nb = (bcol >> 6) + wn;
    const unsigned char* bptr = wq + ((size_t)nb << 18) + fr * 64 + g16;

    i32x4 acc[8][4] = {};
    i32x4 a0[8], b0[4], a1[8], b1[4];        // two static register sets

    // staging: half-tile 128x64 i8 = 8KB = 512 threads x 16B, linear LDS dest;
    // global source chunk pre-swizzled (involution): (tid&3) ^ ((tid>>3)&3).
    const int srow = tid >> 2;
    const int scol = ((tid & 3) ^ ((tid >> 3) & 3)) * 16;
    auto stage = [&](int bufv, int sect, const unsigned char* g, int row0, int k0) {
        async16(g + (size_t)(row0 + srow) * K_DIM + (k0 + scol),
                &lds[bufv][sect][0] + tid * 16);
    };

    // A frag: row = rbase + fr, logical chunk = lane>>4, physical = ^sw
    auto rdA = [&](int bufv, int rbase) -> i32x4 {
        const unsigned char* base = &lds[bufv][wm][0];
        return *(const i32x4*)(base + (rbase + fr) * 64 + (g16 ^ sw));
    };

    // prologue: stage A of tiles 0,1,2; load B(0); drain A(0); preload a0
    STGA(0); STGA(1); STGA(2);
    BLOAD(b0, 0);
    VM8;                 // 10 in flight, keep 8: A(0) landed
    BAR;
    RDSETA(a0, 0);

    // main loop: 2 tiles per iteration, static register-set swap (T=0..59)
    for (int tt = 0; tt < 30; ++tt) {
        const int T = tt * 2;
        ITILE(a0, b0, a1, b1, T);
        ITILE(a1, b1, a0, b0, T + 1);
    }
    ITILE(a0, b0, a1, b1, 60);               // stages A(63), loads T=61 sets
    // tail: tiles 61..63
    BLOAD(b0, 62); RDSETA(a0, 62); MMA(a1, b1); BAR;     // T=61
    BLOAD(b1, 63); RDSETA(a1, 63); MMA(a0, b0); BAR;     // T=62
    MMA(a1, b1);                                         // T=63

    // epilogue: C/D layout col = lane&15, row = (lane>>4)*4 + reg (shape-det.)
    const int wrow = wm * 128, wcol = wn * 64;
    float bv[4];
    #pragma unroll
    for (int n = 0; n < 4; ++n) bv[n] = bias[bcol + wcol + n * 16 + fr];
    const int r4 = (lane >> 4) * 4;
    #pragma unroll
    for (int m = 0; m < 8; ++m) {
        #pragma unroll
        for (int rr = 0; rr < 4; ++rr) {
            const int row = brow + wrow + m * 16 + r4 + rr;
            const float sc = scales[row];
            float* orow = out + (size_t)row * N_DIM + bcol + wcol;
            #pragma unroll
            for (int n = 0; n < 4; ++n)
                orow[n * 16 + fr] = (float)acc[m][n][rr] * sc + bv[n];
        }
    }
}

// ---- Fallback if ws too small: naive fp32 (correct, slow; safety net) ----

__global__ void naive_kernel(const float* __restrict__ x,
                             const float* __restrict__ w,
                             const float* __restrict__ bias,
                             float* __restrict__ out) {
    const size_t total = (size_t)M_DIM * N_DIM;
    for (size_t idx = (size_t)blockIdx.x * blockDim.x + threadIdx.x; idx < total;
         idx += (size_t)gridDim.x * blockDim.x) {
        const size_t row = idx >> 12;
        const size_t col = idx & 4095;
        const float4* xr  = (const float4*)(x + row * K_DIM);
        const float4* wrp = (const float4*)(w + col * K_DIM);
        float s = 0.f;
        for (int k = 0; k < K_DIM / 4; ++k) {
            float4 a = xr[k], bq = wrp[k];
            s += a.x * (bq.x > 0.f ? 1.f : (bq.x < 0.f ? -1.f : 0.f));
            s += a.y * (bq.y > 0.f ? 1.f : (bq.y < 0.f ? -1.f : 0.f));
            s += a.z * (bq.z > 0.f ? 1.f : (bq.z < 0.f ? -1.f : 0.f));
            s += a.w * (bq.w > 0.f ? 1.f : (bq.w < 0.f ? -1.f : 0.f));
        }
        out[idx] = s + bias[col];
    }
}

extern "C" void kernel_launch(void* const* d_in, const int* in_sizes, int n_in,
                              void* d_out, int out_size, void* d_ws, size_t ws_size,
                              hipStream_t stream) {
    const float* x    = (const float*)d_in[0];
    const float* w    = (const float*)d_in[1];
    const float* bias = (const float*)d_in[2];
    float* out = (float*)d_out;

    const size_t xq_bytes = (size_t)M_DIM * K_DIM;       // 32 MB
    const size_t wq_bytes = (size_t)N_DIM * K_DIM;       // 16 MB (retiled)
    const size_t sc_bytes = (size_t)M_DIM * sizeof(float);

    if (ws_size >= xq_bytes + wq_bytes + sc_bytes) {
        unsigned char* xq = (unsigned char*)d_ws;
        unsigned char* wq = (unsigned char*)d_ws + xq_bytes;
        float* scales     = (float*)((char*)d_ws + xq_bytes + wq_bytes);
        convert_w_kernel<<<2048, 256, 0, stream>>>(w, wq,
            (int)((size_t)N_DIM * K_DIM / 4));
        convert_x_kernel<<<M_DIM, 256, 0, stream>>>(x, xq, scales);
        gemm_bin_kernel<<<dim3((M_DIM / 256) * (N_DIM / 256)), dim3(512), 0, stream>>>(
            xq, wq, scales, bias, out);
    } else {
        naive_kernel<<<4096, 256, 0, stream>>>(x, w, bias, out);
    }
}

// Round 14
// 194.452 us; speedup vs baseline: 1.0264x; 1.0264x over previous
//
#include <hip/hip_runtime.h>
#include <hip/hip_bf16.h>
#include <stdint.h>

#define M_DIM 8192
#define N_DIM 4096
#define K_DIM 4096

#define NT 64              // K-tiles of BK=64

using i32x4  = __attribute__((ext_vector_type(4))) int;
using i32x16 = __attribute__((ext_vector_type(16))) int;

typedef const __attribute__((address_space(1))) void glb_void_t;
typedef __attribute__((address_space(3))) void lds_void_t;

__device__ __forceinline__ void async16(const void* g, void* l) {
    // direct global->LDS, 16B per lane (dest = wave-uniform base + lane*16)
    __builtin_amdgcn_global_load_lds((glb_void_t*)(uintptr_t)g,
                                     (lds_void_t*)(uint32_t)(uintptr_t)l,
                                     16, 0, 0);
}

__device__ __forceinline__ int sgn_i8(float f) {
    union { float f; uint32_t u; } v; v.f = f;
    if ((v.u & 0x7FFFFFFFu) == 0u) return 0;          // sign(0) = 0
    return (v.u >> 31) ? -1 : 1;
}

// ---- Phase 1a: W sign -> i8 {-1,0,+1}. 64MB read, 16MB write ----

__global__ void convert_w_kernel(const float* __restrict__ w,
                                 unsigned char* __restrict__ wq, int n4) {
    int stride = gridDim.x * blockDim.x;
    for (int i = blockIdx.x * blockDim.x + threadIdx.x; i < n4; i += stride) {
        float4 v = ((const float4*)w)[i];
        uint32_t o = ((uint32_t)(uint8_t)sgn_i8(v.x)) |
                     ((uint32_t)(uint8_t)sgn_i8(v.y) << 8) |
                     ((uint32_t)(uint8_t)sgn_i8(v.z) << 16) |
                     ((uint32_t)(uint8_t)sgn_i8(v.w) << 24);
        ((uint32_t*)wq)[i] = o;
    }
}

// ---- Phase 1b: X per-row i8 quant (fused max + quantize, single pass) ----

__global__ __launch_bounds__(256)
void convert_x_kernel(const float* __restrict__ x,
                      unsigned char* __restrict__ xq,
                      float* __restrict__ scales) {
    const int row = blockIdx.x;
    const int tid = threadIdx.x;
    const float4* xr = (const float4*)(x + (size_t)row * K_DIM);
    float4 v[4];
    float m = 0.f;
    #pragma unroll
    for (int j = 0; j < 4; ++j) {
        v[j] = xr[j * 256 + tid];
        m = fmaxf(m, fmaxf(fmaxf(fabsf(v[j].x), fabsf(v[j].y)),
                           fmaxf(fabsf(v[j].z), fabsf(v[j].w))));
    }
    #pragma unroll
    for (int off = 32; off >= 1; off >>= 1)
        m = fmaxf(m, __shfl_xor(m, off));
    __shared__ float wmax[4];
    if ((tid & 63) == 0) wmax[tid >> 6] = m;
    __syncthreads();
    m = fmaxf(fmaxf(wmax[0], wmax[1]), fmaxf(wmax[2], wmax[3]));
    const float inv = (m > 0.f) ? 127.0f / m : 0.f;
    if (tid == 0) scales[row] = (m > 0.f) ? m / 127.0f : 0.f;
    uint32_t* oq = (uint32_t*)(xq + (size_t)row * K_DIM);
    #pragma unroll
    for (int j = 0; j < 4; ++j) {
        float q0 = fminf(fmaxf(rintf(v[j].x * inv), -127.f), 127.f);
        float q1 = fminf(fmaxf(rintf(v[j].y * inv), -127.f), 127.f);
        float q2 = fminf(fmaxf(rintf(v[j].z * inv), -127.f), 127.f);
        float q3 = fminf(fmaxf(rintf(v[j].w * inv), -127.f), 127.f);
        uint32_t o = ((uint32_t)(uint8_t)(int)q0) |
                     ((uint32_t)(uint8_t)(int)q1 << 8) |
                     ((uint32_t)(uint8_t)(int)q2 << 16) |
                     ((uint32_t)(uint8_t)(int)q3 << 24);
        oq[j * 256 + tid] = o;
    }
}

// ---- Phase 2: 256x256-tile i8 GEMM, mfma_i32_32x32x32_i8, reg-dbuf ----
// Round 14: round 12 structure with the 32x32x32 i8 shape (4404 TOPS ubench
// vs 3944 for 16x16x64 -> per-tile MFMA 1306 -> 1165 cyc/CU). Same frag
// bytes (16B/lane, ds_read_b128), same acc budget (4x2 x i32x16 = 128), same
// staging/swizzle. A/B frag: row = lane&31, kbyte = kk*32 + (lane>>5)*16.
// Bank check under the existing chunk-XOR swizzle (chunk ^= (row>>1)&3):
// each 8-lane phase covers all 8 bank-groups exactly once -> 0 conflicts.
// LDS: [4 buf][4 sect: A0,A1,B0,B1][128 x 64 i8] = 128 KiB; buf = T&3;
// tile T stages T+3. Sync ledger (1 barrier/tile, unchanged from r11/r12):
//   End-of-T vmcnt(4) leaves only (T+3)'s 4 loads => T+2 landed; BAR
//   publishes => tile T+1's body reads T+2's LDS safely.
//   Buf (T+3)&3 WAR: its last ds_reads ran in tile T-2, retired before tile
//   T-1's consuming MFMAs, which precede BAR(T-1) < stage at T.

#define BAR   __builtin_amdgcn_s_barrier()
#define VM4   asm volatile("s_waitcnt vmcnt(4)" ::: "memory")
#define VM0   asm volatile("s_waitcnt vmcnt(0)" ::: "memory")
#define SGB_DS(N)   __builtin_amdgcn_sched_group_barrier(0x100, (N), 0)
#define SGB_MFMA(N) __builtin_amdgcn_sched_group_barrier(0x008, (N), 0)

// stage all four half-tiles of tile T into buf T&3
#define STG(T) do { \
    const int pb_ = (T) & 3; \
    stage(pb_, 0, xq, brow,       (T) * 64); \
    stage(pb_, 1, xq, brow + 128, (T) * 64); \
    stage(pb_, 2, wq, bcol,       (T) * 64); \
    stage(pb_, 3, wq, bcol + 128, (T) * 64); \
} while (0)

// read all 12 fragments of tile T into register set (AV, BV)  [tail use]
// AV[kk*4+mm], BV[kk*2+nn]
#define RDSET(AV, BV, T) do { \
    const int rb_ = (T) & 3; \
    _Pragma("unroll") for (int kk = 0; kk < 2; ++kk) { \
        _Pragma("unroll") for (int nn = 0; nn < 2; ++nn) \
            BV[kk * 2 + nn] = rdfrag(rb_, sectB, rB + nn * 32, kk); \
        _Pragma("unroll") for (int mm = 0; mm < 4; ++mm) \
            AV[kk * 4 + mm] = rdfrag(rb_, wm, mm * 32, kk); \
    } \
} while (0)

// all 16 MFMAs of one tile  [tail use]
#define MMA(AV, BV) do { \
    __builtin_amdgcn_s_setprio(1); \
    _Pragma("unroll") for (int kk = 0; kk < 2; ++kk) \
    _Pragma("unroll") for (int mm = 0; mm < 4; ++mm) \
    _Pragma("unroll") for (int nn = 0; nn < 2; ++nn) \
        acc[mm][nn] = __builtin_amdgcn_mfma_i32_32x32x32_i8( \
            AV[kk * 4 + mm], BV[kk * 2 + nn], acc[mm][nn], 0, 0, 0); \
    __builtin_amdgcn_s_setprio(0); \
} while (0)

// 4 MFMAs: one m-block (both kk, both nn)
#define MM4(AV, BV, M0) \
    _Pragma("unroll") for (int kk = 0; kk < 2; ++kk) \
    _Pragma("unroll") for (int nn = 0; nn < 2; ++nn) \
        acc[(M0)][nn] = __builtin_amdgcn_mfma_i32_32x32x32_i8( \
            AV[kk * 4 + (M0)], BV[kk * 2 + nn], acc[(M0)][nn], 0, 0, 0);

// steady-state tile T: MFMA tile T from (CA,CB); read tile T+1 into (NA,NB);
// stage tile T+3; pinned 3-reads/4-MFMA x4.
#define ITILE(CA, CB, NA, NB, T) do { \
    const int rb_ = ((T) + 1) & 3; \
    STG((T) + 3); \
    __builtin_amdgcn_s_setprio(1); \
    NB[0] = rdfrag(rb_, sectB, rB,      0); \
    NB[1] = rdfrag(rb_, sectB, rB + 32, 0); \
    NB[2] = rdfrag(rb_, sectB, rB,      1); \
    MM4(CA, CB, 0) \
    NB[3] = rdfrag(rb_, sectB, rB + 32, 1); \
    NA[0] = rdfrag(rb_, wm,  0, 0); \
    NA[4] = rdfrag(rb_, wm,  0, 1); \
    MM4(CA, CB, 1) \
    NA[1] = rdfrag(rb_, wm, 32, 0); \
    NA[5] = rdfrag(rb_, wm, 32, 1); \
    NA[2] = rdfrag(rb_, wm, 64, 0); \
    MM4(CA, CB, 2) \
    NA[6] = rdfrag(rb_, wm, 64, 1); \
    NA[3] = rdfrag(rb_, wm, 96, 0); \
    NA[7] = rdfrag(rb_, wm, 96, 1); \
    MM4(CA, CB, 3) \
    SGB_DS(3); SGB_MFMA(4); \
    SGB_DS(3); SGB_MFMA(4); \
    SGB_DS(3); SGB_MFMA(4); \
    SGB_DS(3); SGB_MFMA(4); \
    __builtin_amdgcn_s_setprio(0); \
    VM4; BAR; \
} while (0)

__global__ __launch_bounds__(512, 2)
void gemm_bin_kernel(const unsigned char* __restrict__ xq,
                     const unsigned char* __restrict__ wq,
                     const float* __restrict__ scales,
                     const float* __restrict__ bias,
                     float* __restrict__ out) {
    __shared__ __align__(16) unsigned char lds[4][4][8192];

    const int tid  = threadIdx.x;
    const int wid  = tid >> 6;
    const int lane = tid & 63;

    // XCD-aware swizzle: 512 blocks, 8 XCDs, 64 contiguous tiles per XCD
    const int bid  = blockIdx.x;
    const int swzb = (bid & 7) * 64 + (bid >> 3);
    const int brow = (swzb >> 4) * 256;      // 32 M-tiles
    const int bcol = (swzb & 15) * 256;      // 16 N-tiles

    const int wm = wid >> 2;                 // 0..1: A half (row block of 128)
    const int wn = wid & 3;                  // 0..3: 64-col block
    const int l31 = lane & 31;
    const int h16 = (lane >> 5) << 4;        // 16B half within a k-slot
    const int sw  = ((lane >> 1) & 3) << 4;  // T2: ((row>>1)&3)<<4, row=l31+32m
    const int sectB = 2 + (wn >> 1);
    const int rB    = (wn & 1) * 64;

    i32x16 acc[4][2] = {};                   // 4 m-blocks x 2 n-blocks of 32x32
    i32x4 a0[8], b0[4], a1[8], b1[4];        // two static register sets

    // staging: half-tile 128x64 i8 = 8KB = 512 threads x 16B, linear LDS dest;
    // global source chunk pre-swizzled (involution): (tid&3) ^ ((tid>>3)&3).
    const int srow = tid >> 2;
    const int scol = ((tid & 3) ^ ((tid >> 3) & 3)) * 16;
    auto stage = [&](int bufv, int sect, const unsigned char* g, int row0, int k0) {
        async16(g + (size_t)(row0 + srow) * K_DIM + (k0 + scol),
                &lds[bufv][sect][0] + tid * 16);
    };

    // 32x32x32 i8 frag: row = rbase + (lane&31), logical kbyte = kk*32 + h16,
    // physical = logical ^ ((row>>1)&3)<<4  (sw precomputed; rbase%32==0)
    auto rdfrag = [&](int bufv, int sect, int rbase, int kk) -> i32x4 {
        const unsigned char* base = &lds[bufv][sect][0];
        return *(const i32x4*)(base + (rbase + l31) * 64 + ((kk * 32 + h16) ^ sw));
    };

    // prologue: stage tiles 0,1,2; drain 0,1 (keep 2 in flight); preload t0 regs
    STG(0); STG(1); STG(2);
    VM4;                 // 12 issued, keep 4 newest (tile 2): tiles 0,1 landed
    BAR;
    RDSET(a0, b0, 0);

    // main loop: 2 tiles per iteration, static register-set swap
    for (int tt = 0; tt < 30; ++tt) {
        const int T = tt * 2;
        ITILE(a0, b0, a1, b1, T);
        ITILE(a1, b1, a0, b0, T + 1);
    }
    // tail: tiles 60..63 (as round 12)
    STG(63); RDSET(a1, b1, 61); MMA(a0, b0); VM4; BAR;   // 62 landed
    RDSET(a0, b0, 62); MMA(a1, b1); VM0; BAR;            // 63 landed
    RDSET(a1, b1, 63); MMA(a0, b0);                      // tile 62
    MMA(a1, b1);                                         // tile 63

    // epilogue: 32x32 C/D: col = lane&31, row = (reg&3)+8*(reg>>2)+4*(lane>>5)
    const int wrow = wm * 128, wcol = wn * 64;
    const int h4 = (lane >> 5) * 4;
    float bv[2];
    #pragma unroll
    for (int nb = 0; nb < 2; ++nb) bv[nb] = bias[bcol + wcol + nb * 32 + l31];
    #pragma unroll
    for (int mb = 0; mb < 4; ++mb) {
        #pragma unroll
        for (int rg = 0; rg < 4; ++rg) {
            #pragma unroll
            for (int rr = 0; rr < 4; ++rr) {
                const int row = brow + wrow + mb * 32 + rg * 8 + h4 + rr;
                const float sc = scales[row];
                float* orow = out + (size_t)row * N_DIM + bcol + wcol;
                #pragma unroll
                for (int nb = 0; nb < 2; ++nb)
                    orow[nb * 32 + l31] = (float)acc[mb][nb][rg * 4 + rr] * sc + bv[nb];
            }
        }
    }
}

// ---- Fallback if ws too small: naive fp32 (correct, slow; safety net) ----

__global__ void naive_kernel(const float* __restrict__ x,
                             const float* __restrict__ w,
                             const float* __restrict__ bias,
                             float* __restrict__ out) {
    const size_t total = (size_t)M_DIM * N_DIM;
    for (size_t idx = (size_t)blockIdx.x * blockDim.x + threadIdx.x; idx < total;
         idx += (size_t)gridDim.x * blockDim.x) {
        const size_t row = idx >> 12;
        const size_t col = idx & 4095;
        const float4* xr  = (const float4*)(x + row * K_DIM);
        const float4* wrp = (const float4*)(w + col * K_DIM);
        float s = 0.f;
        for (int k = 0; k < K_DIM / 4; ++k) {
            float4 a = xr[k], bq = wrp[k];
            s += a.x * (bq.x > 0.f ? 1.f : (bq.x < 0.f ? -1.f : 0.f));
            s += a.y * (bq.y > 0.f ? 1.f : (bq.y < 0.f ? -1.f : 0.f));
            s += a.z * (bq.z > 0.f ? 1.f : (bq.z < 0.f ? -1.f : 0.f));
            s += a.w * (bq.w > 0.f ? 1.f : (bq.w < 0.f ? -1.f : 0.f));
        }
        out[idx] = s + bias[col];
    }
}

extern "C" void kernel_launch(void* const* d_in, const int* in_sizes, int n_in,
                              void* d_out, int out_size, void* d_ws, size_t ws_size,
                              hipStream_t stream) {
    const float* x    = (const float*)d_in[0];
    const float* w    = (const float*)d_in[1];
    const float* bias = (const float*)d_in[2];
    float* out = (float*)d_out;

    const size_t xq_bytes = (size_t)M_DIM * K_DIM;       // 32 MB
    const size_t wq_bytes = (size_t)N_DIM * K_DIM;       // 16 MB
    const size_t sc_bytes = (size_t)M_DIM * sizeof(float);

    if (ws_size >= xq_bytes + wq_bytes + sc_bytes) {
        unsigned char* xq = (unsigned char*)d_ws;
        unsigned char* wq = (unsigned char*)d_ws + xq_bytes;
        float* scales     = (float*)((char*)d_ws + xq_bytes + wq_bytes);
        convert_w_kernel<<<2048, 256, 0, stream>>>(w, wq,
            (int)((size_t)N_DIM * K_DIM / 4));
        convert_x_kernel<<<M_DIM, 256, 0, stream>>>(x, xq, scales);
        gemm_bin_kernel<<<dim3((M_DIM / 256) * (N_DIM / 256)), dim3(512), 0, stream>>>(
            xq, wq, scales, bias, out);
    } else {
        naive_kernel<<<4096, 256, 0, stream>>>(x, w, bias, out);
    }
}

// Round 15
// 181.423 us; speedup vs baseline: 1.1001x; 1.0718x over previous
//
#include <hip/hip_runtime.h>
#include <hip/hip_bf16.h>
#include <stdint.h>

#define M_DIM 8192
#define N_DIM 4096
#define K_DIM 4096

#define NT 64              // K-tiles of BK=64

using i32x4 = __attribute__((ext_vector_type(4))) int;

typedef const __attribute__((address_space(1))) void glb_void_t;
typedef __attribute__((address_space(3))) void lds_void_t;

__device__ __forceinline__ void async16(const void* g, void* l) {
    // direct global->LDS, 16B per lane (dest = wave-uniform base + lane*16)
    __builtin_amdgcn_global_load_lds((glb_void_t*)(uintptr_t)g,
                                     (lds_void_t*)(uint32_t)(uintptr_t)l,
                                     16, 0, 0);
}

__device__ __forceinline__ int sgn_i8(float f) {
    union { float f; uint32_t u; } v; v.f = f;
    if ((v.u & 0x7FFFFFFFu) == 0u) return 0;          // sign(0) = 0
    return (v.u >> 31) ? -1 : 1;
}

// ---- Phase 1 (fused): blocks [0, M) = per-row X i8 quant;
//      blocks [M, M+2048) = grid-stride W sign -> i8. One dispatch: the two
//      memory streams overlap (tail + launch overhead reclaimed vs 2 kernels).

__global__ __launch_bounds__(256)
void convert_fused_kernel(const float* __restrict__ x,
                          const float* __restrict__ w,
                          unsigned char* __restrict__ xq,
                          unsigned char* __restrict__ wq,
                          float* __restrict__ scales) {
    __shared__ float wmax[4];
    const int tid = threadIdx.x;

    if (blockIdx.x < M_DIM) {
        // ---- X per-row quant: scale = rowmax/127, q = rne(x*127/rowmax).
        // i32 accum in the GEMM is exact, so quant error is the only error.
        const int row = blockIdx.x;
        const float4* xr = (const float4*)(x + (size_t)row * K_DIM);
        float4 v[4];
        float m = 0.f;
        #pragma unroll
        for (int j = 0; j < 4; ++j) {
            v[j] = xr[j * 256 + tid];
            m = fmaxf(m, fmaxf(fmaxf(fabsf(v[j].x), fabsf(v[j].y)),
                               fmaxf(fabsf(v[j].z), fabsf(v[j].w))));
        }
        #pragma unroll
        for (int off = 32; off >= 1; off >>= 1)
            m = fmaxf(m, __shfl_xor(m, off));
        if ((tid & 63) == 0) wmax[tid >> 6] = m;
        __syncthreads();
        m = fmaxf(fmaxf(wmax[0], wmax[1]), fmaxf(wmax[2], wmax[3]));
        const float inv = (m > 0.f) ? 127.0f / m : 0.f;
        if (tid == 0) scales[row] = (m > 0.f) ? m / 127.0f : 0.f;
        uint32_t* oq = (uint32_t*)(xq + (size_t)row * K_DIM);
        #pragma unroll
        for (int j = 0; j < 4; ++j) {
            float q0 = fminf(fmaxf(rintf(v[j].x * inv), -127.f), 127.f);
            float q1 = fminf(fmaxf(rintf(v[j].y * inv), -127.f), 127.f);
            float q2 = fminf(fmaxf(rintf(v[j].z * inv), -127.f), 127.f);
            float q3 = fminf(fmaxf(rintf(v[j].w * inv), -127.f), 127.f);
            uint32_t o = ((uint32_t)(uint8_t)(int)q0) |
                         ((uint32_t)(uint8_t)(int)q1 << 8) |
                         ((uint32_t)(uint8_t)(int)q2 << 16) |
                         ((uint32_t)(uint8_t)(int)q3 << 24);
            oq[j * 256 + tid] = o;
        }
    } else {
        // ---- W sign -> i8 {-1,0,+1}: 64MB read, 16MB write, grid-stride.
        const int n4 = N_DIM * K_DIM / 4;
        const int stride = 2048 * 256;
        for (int i = (blockIdx.x - M_DIM) * 256 + tid; i < n4; i += stride) {
            float4 v = ((const float4*)w)[i];
            uint32_t o = ((uint32_t)(uint8_t)sgn_i8(v.x)) |
                         ((uint32_t)(uint8_t)sgn_i8(v.y) << 8) |
                         ((uint32_t)(uint8_t)sgn_i8(v.z) << 16) |
                         ((uint32_t)(uint8_t)sgn_i8(v.w) << 24);
            ((uint32_t*)wq)[i] = o;
        }
    }
}

// ---- Phase 2: 256x256-tile i8 GEMM, reg-dbuf + pinned DS/MFMA interleave ----
// (round-12 kernel verbatim - best measured: 133.1 us, 0 bank conflicts)
// During tile T each wave MFMAs from register set CUR (loaded during T-1)
// while issuing the 12 ds_reads of tile T+1 into set NEXT, pinned 3-reads/
// 8-MFMA x4 via sched_group_barrier.
// LDS: [4 buf][4 sect: A0,A1,B0,B1][128 x 64 i8] = 128 KiB; buf = T&3;
// tile T stages T+3. T2 chunk-XOR swizzle (round-8-proven, 0 conflicts).
// Sync ledger (1 barrier/tile):
//   End-of-T vmcnt(4) leaves only (T+3)'s 4 loads => T+2 landed; BAR
//   publishes => tile T+1's body reads T+2's LDS safely.
//   Buf (T+3)&3 WAR: its last ds_reads ran in tile T-2, retired before tile
//   T-1's consuming MFMAs, which precede BAR(T-1) < stage at T.

#define BAR   __builtin_amdgcn_s_barrier()
#define VM4   asm volatile("s_waitcnt vmcnt(4)" ::: "memory")
#define VM0   asm volatile("s_waitcnt vmcnt(0)" ::: "memory")
#define SGB_DS(N)   __builtin_amdgcn_sched_group_barrier(0x100, (N), 0)
#define SGB_MFMA(N) __builtin_amdgcn_sched_group_barrier(0x008, (N), 0)

// stage all four half-tiles of tile T into buf T&3
#define STG(T) do { \
    const int pb_ = (T) & 3; \
    stage(pb_, 0, xq, brow,       (T) * 64); \
    stage(pb_, 1, xq, brow + 128, (T) * 64); \
    stage(pb_, 2, wq, bcol,       (T) * 64); \
    stage(pb_, 3, wq, bcol + 128, (T) * 64); \
} while (0)

// read all 12 fragments of tile T into register set (AV, BV)  [tail use]
#define RDSET(AV, BV, T) do { \
    const int rb_ = (T) & 3; \
    _Pragma("unroll") for (int nn = 0; nn < 4; ++nn) \
        BV[nn] = rdfrag(rb_, sectB, rB + nn * 16); \
    _Pragma("unroll") for (int mm = 0; mm < 8; ++mm) \
        AV[mm] = rdfrag(rb_, wm, mm * 16); \
} while (0)

// all 32 MFMAs of one tile from register set (AV, BV)  [tail use]
#define MMA(AV, BV) do { \
    __builtin_amdgcn_s_setprio(1); \
    _Pragma("unroll") for (int mm = 0; mm < 8; ++mm) \
    _Pragma("unroll") for (int nn = 0; nn < 4; ++nn) \
        acc[mm][nn] = __builtin_amdgcn_mfma_i32_16x16x64_i8( \
            AV[mm], BV[nn], acc[mm][nn], 0, 0, 0); \
    __builtin_amdgcn_s_setprio(0); \
} while (0)

// 8 MFMAs (2 m-rows) of the current tile
#define MM2(AV, BV, M0) \
    _Pragma("unroll") for (int mm = (M0); mm < (M0) + 2; ++mm) \
    _Pragma("unroll") for (int nn = 0; nn < 4; ++nn) \
        acc[mm][nn] = __builtin_amdgcn_mfma_i32_16x16x64_i8( \
            AV[mm], BV[nn], acc[mm][nn], 0, 0, 0);

// steady-state tile T: MFMA tile T from (CA,CB); read tile T+1 into (NA,NB);
// stage tile T+3; interleave pinned 3-reads/8-MFMA x4.
#define ITILE(CA, CB, NA, NB, T) do { \
    const int rb_ = ((T) + 1) & 3; \
    STG((T) + 3); \
    __builtin_amdgcn_s_setprio(1); \
    NB[0] = rdfrag(rb_, sectB, rB +  0); \
    NB[1] = rdfrag(rb_, sectB, rB + 16); \
    NB[2] = rdfrag(rb_, sectB, rB + 32); \
    MM2(CA, CB, 0) \
    NB[3] = rdfrag(rb_, sectB, rB + 48); \
    NA[0] = rdfrag(rb_, wm,   0); \
    NA[1] = rdfrag(rb_, wm,  16); \
    MM2(CA, CB, 2) \
    NA[2] = rdfrag(rb_, wm,  32); \
    NA[3] = rdfrag(rb_, wm,  48); \
    NA[4] = rdfrag(rb_, wm,  64); \
    MM2(CA, CB, 4) \
    NA[5] = rdfrag(rb_, wm,  80); \
    NA[6] = rdfrag(rb_, wm,  96); \
    NA[7] = rdfrag(rb_, wm, 112); \
    MM2(CA, CB, 6) \
    SGB_DS(3); SGB_MFMA(8); \
    SGB_DS(3); SGB_MFMA(8); \
    SGB_DS(3); SGB_MFMA(8); \
    SGB_DS(3); SGB_MFMA(8); \
    __builtin_amdgcn_s_setprio(0); \
    VM4; BAR; \
} while (0)

__global__ __launch_bounds__(512, 2)
void gemm_bin_kernel(const unsigned char* __restrict__ xq,
                     const unsigned char* __restrict__ wq,
                     const float* __restrict__ scales,
                     const float* __restrict__ bias,
                     float* __restrict__ out) {
    __shared__ __align__(16) unsigned char lds[4][4][8192];

    const int tid  = threadIdx.x;
    const int wid  = tid >> 6;
    const int lane = tid & 63;

    // XCD-aware swizzle: 512 blocks, 8 XCDs, 64 contiguous tiles per XCD
    const int bid  = blockIdx.x;
    const int swzb = (bid & 7) * 64 + (bid >> 3);
    const int brow = (swzb >> 4) * 256;      // 32 M-tiles
    const int bcol = (swzb & 15) * 256;      // 16 N-tiles

    const int wm = wid >> 2;                 // 0..1: A half (row block of 128)
    const int wn = wid & 3;                  // 0..3: 64-col block
    const int fr  = lane & 15;
    const int g16 = (lane >> 4) << 4;        // logical k-chunk byte offset
    const int sw  = ((lane >> 1) & 3) << 4;  // T2: ((row>>1)&3)<<4, row=fr+16m
    const int sectB = 2 + (wn >> 1);
    const int rB    = (wn & 1) * 64;

    i32x4 acc[8][4] = {};
    i32x4 a0[8], b0[4], a1[8], b1[4];        // two static register sets

    // staging: half-tile 128x64 i8 = 8KB = 512 threads x 16B, linear LDS dest;
    // global source chunk pre-swizzled (involution): (tid&3) ^ ((tid>>3)&3).
    const int srow = tid >> 2;
    const int scol = ((tid & 3) ^ ((tid >> 3) & 3)) * 16;
    auto stage = [&](int bufv, int sect, const unsigned char* g, int row0, int k0) {
        async16(g + (size_t)(row0 + srow) * K_DIM + (k0 + scol),
                &lds[bufv][sect][0] + tid * 16);
    };

    // 16x16x64 i8 frag: row = rbase + fr, logical chunk = lane>>4,
    // physical chunk = logical ^ ((row>>1)&3)  (sw precomputed)
    auto rdfrag = [&](int bufv, int sect, int rbase) -> i32x4 {
        const unsigned char* base = &lds[bufv][sect][0];
        return *(const i32x4*)(base + (rbase + fr) * 64 + (g16 ^ sw));
    };

    // prologue: stage tiles 0,1,2; drain 0,1 (keep 2 in flight); preload t0 regs
    STG(0); STG(1); STG(2);
    VM4;                 // 12 issued, keep 4 newest (tile 2): tiles 0,1 landed
    BAR;
    RDSET(a0, b0, 0);

    // main loop: 2 tiles per iteration, static register-set swap
    for (int tt = 0; tt < 30; ++tt) {
        const int T = tt * 2;
        ITILE(a0, b0, a1, b1, T);
        ITILE(a1, b1, a0, b0, T + 1);
    }
    // tail: tiles 60..63
    STG(63); RDSET(a1, b1, 61); MMA(a0, b0); VM4; BAR;   // 62 landed
    RDSET(a0, b0, 62); MMA(a1, b1); VM0; BAR;            // 63 landed
    RDSET(a1, b1, 63); MMA(a0, b0);                      // tile 62
    MMA(a1, b1);                                         // tile 63

    // epilogue: C/D layout col = lane&15, row = (lane>>4)*4 + reg (shape-det.)
    const int wrow = wm * 128, wcol = wn * 64;
    float bv[4];
    #pragma unroll
    for (int n = 0; n < 4; ++n) bv[n] = bias[bcol + wcol + n * 16 + fr];
    const int r4 = (lane >> 4) * 4;
    #pragma unroll
    for (int m = 0; m < 8; ++m) {
        #pragma unroll
        for (int rr = 0; rr < 4; ++rr) {
            const int row = brow + wrow + m * 16 + r4 + rr;
            const float sc = scales[row];
            float* orow = out + (size_t)row * N_DIM + bcol + wcol;
            #pragma unroll
            for (int n = 0; n < 4; ++n)
                orow[n * 16 + fr] = (float)acc[m][n][rr] * sc + bv[n];
        }
    }
}

// ---- Fallback if ws too small: naive fp32 (correct, slow; safety net) ----

__global__ void naive_kernel(const float* __restrict__ x,
                             const float* __restrict__ w,
                             const float* __restrict__ bias,
                             float* __restrict__ out) {
    const size_t total = (size_t)M_DIM * N_DIM;
    for (size_t idx = (size_t)blockIdx.x * blockDim.x + threadIdx.x; idx < total;
         idx += (size_t)gridDim.x * blockDim.x) {
        const size_t row = idx >> 12;
        const size_t col = idx & 4095;
        const float4* xr  = (const float4*)(x + row * K_DIM);
        const float4* wrp = (const float4*)(w + col * K_DIM);
        float s = 0.f;
        for (int k = 0; k < K_DIM / 4; ++k) {
            float4 a = xr[k], bq = wrp[k];
            s += a.x * (bq.x > 0.f ? 1.f : (bq.x < 0.f ? -1.f : 0.f));
            s += a.y * (bq.y > 0.f ? 1.f : (bq.y < 0.f ? -1.f : 0.f));
            s += a.z * (bq.z > 0.f ? 1.f : (bq.z < 0.f ? -1.f : 0.f));
            s += a.w * (bq.w > 0.f ? 1.f : (bq.w < 0.f ? -1.f : 0.f));
        }
        out[idx] = s + bias[col];
    }
}

extern "C" void kernel_launch(void* const* d_in, const int* in_sizes, int n_in,
                              void* d_out, int out_size, void* d_ws, size_t ws_size,
                              hipStream_t stream) {
    const float* x    = (const float*)d_in[0];
    const float* w    = (const float*)d_in[1];
    const float* bias = (const float*)d_in[2];
    float* out = (float*)d_out;

    const size_t xq_bytes = (size_t)M_DIM * K_DIM;       // 32 MB
    const size_t wq_bytes = (size_t)N_DIM * K_DIM;       // 16 MB
    const size_t sc_bytes = (size_t)M_DIM * sizeof(float);

    if (ws_size >= xq_bytes + wq_bytes + sc_bytes) {
        unsigned char* xq = (unsigned char*)d_ws;
        unsigned char* wq = (unsigned char*)d_ws + xq_bytes;
        float* scales     = (float*)((char*)d_ws + xq_bytes + wq_bytes);
        convert_fused_kernel<<<M_DIM + 2048, 256, 0, stream>>>(x, w, xq, wq, scales);
        gemm_bin_kernel<<<dim3((M_DIM / 256) * (N_DIM / 256)), dim3(512), 0, stream>>>(
            xq, wq, scales, bias, out);
    } else {
        naive_kernel<<<4096, 256, 0, stream>>>(x, w, bias, out);
    }
}